// Round 1
// baseline (3188.822 us; speedup 1.0000x reference)
//
#include <hip/hip_runtime.h>
#include <math.h>

// Problem dims (fixed)
#define BB   16
#define SS   2048
#define DIN  256
#define DEMB 512
#define DKQ  512
#define DVV  512

// ---------------------------------------------------------------------------
// Kernel 1: fuse weights  W'{k,q,v} = W_embed @ W_{k,q,v}   [256 x 512]
// Grid: 1536 blocks x 256 threads (3 * 256 * 512 outputs)
// ---------------------------------------------------------------------------
__global__ __launch_bounds__(256) void fuse_weights(
    const float* __restrict__ We, const float* __restrict__ Wk,
    const float* __restrict__ Wq, const float* __restrict__ Wv,
    float* __restrict__ Wk2, float* __restrict__ Wq2, float* __restrict__ Wv2)
{
    int idx = blockIdx.x * 256 + threadIdx.x;   // [0, 3*131072)
    int n = idx & 511;
    int m = (idx >> 9) & 255;
    int w = idx >> 17;
    const float* Wsrc = (w == 0) ? Wk : (w == 1) ? Wq : Wv;
    float* Wdst       = (w == 0) ? Wk2 : (w == 1) ? Wq2 : Wv2;
    float sum = 0.f;
#pragma unroll 8
    for (int kk = 0; kk < DEMB; ++kk)
        sum += We[m * DEMB + kk] * Wsrc[kk * 512 + n];
    Wdst[m * 512 + n] = sum;
}

// ---------------------------------------------------------------------------
// Kernel 2: projections  {K,Q,V} = X @ W'{k,q,v}
// X: [32768 x 256], W': [256 x 512], Out: [32768 x 512]
// 64x64 tile, K-tile 16, 256 threads, 4x4 microtile per thread.
// Grid: (8, 512, 3)
// ---------------------------------------------------------------------------
__global__ __launch_bounds__(256) void qkv_gemm(
    const float* __restrict__ X,
    const float* __restrict__ Wk2, const float* __restrict__ Wq2,
    const float* __restrict__ Wv2,
    float* __restrict__ Kb, float* __restrict__ Qb, float* __restrict__ Vb)
{
    const float* Wp = (blockIdx.z == 0) ? Wk2 : (blockIdx.z == 1) ? Wq2 : Wv2;
    float* Out      = (blockIdx.z == 0) ? Kb  : (blockIdx.z == 1) ? Qb  : Vb;

    __shared__ float As[64][17];
    __shared__ float Bs[16][65];

    const int tid = threadIdx.x;
    const int tx = tid & 15, ty = tid >> 4;
    const int m0 = blockIdx.y * 64, n0 = blockIdx.x * 64;

    float c[4][4] = {};

    for (int k0 = 0; k0 < DIN; k0 += 16) {
        {   // A tile 64x16: one float4 per thread
            int row = tid >> 2, c4 = tid & 3;
            float4 a = *(const float4*)&X[(size_t)(m0 + row) * DIN + k0 + c4 * 4];
            As[row][c4 * 4 + 0] = a.x; As[row][c4 * 4 + 1] = a.y;
            As[row][c4 * 4 + 2] = a.z; As[row][c4 * 4 + 3] = a.w;
        }
        {   // B tile 16x64: one float4 per thread
            int row = tid >> 4, c4 = tid & 15;
            float4 b = *(const float4*)&Wp[(size_t)(k0 + row) * 512 + n0 + c4 * 4];
            Bs[row][c4 * 4 + 0] = b.x; Bs[row][c4 * 4 + 1] = b.y;
            Bs[row][c4 * 4 + 2] = b.z; Bs[row][c4 * 4 + 3] = b.w;
        }
        __syncthreads();
#pragma unroll
        for (int kk = 0; kk < 16; ++kk) {
            float a0 = As[ty * 4 + 0][kk], a1 = As[ty * 4 + 1][kk];
            float a2 = As[ty * 4 + 2][kk], a3 = As[ty * 4 + 3][kk];
            float b0 = Bs[kk][tx * 4 + 0], b1 = Bs[kk][tx * 4 + 1];
            float b2 = Bs[kk][tx * 4 + 2], b3 = Bs[kk][tx * 4 + 3];
            c[0][0] += a0 * b0; c[0][1] += a0 * b1; c[0][2] += a0 * b2; c[0][3] += a0 * b3;
            c[1][0] += a1 * b0; c[1][1] += a1 * b1; c[1][2] += a1 * b2; c[1][3] += a1 * b3;
            c[2][0] += a2 * b0; c[2][1] += a2 * b1; c[2][2] += a2 * b2; c[2][3] += a2 * b3;
            c[3][0] += a3 * b0; c[3][1] += a3 * b1; c[3][2] += a3 * b2; c[3][3] += a3 * b3;
        }
        __syncthreads();
    }
#pragma unroll
    for (int i = 0; i < 4; ++i) {
        float4 o = make_float4(c[i][0], c[i][1], c[i][2], c[i][3]);
        *(float4*)&Out[(size_t)(m0 + ty * 4 + i) * 512 + n0 + tx * 4] = o;
    }
}

// ---------------------------------------------------------------------------
// Kernel 3: flash-style attention (fp32, unscaled scores, online softmax)
// Per block: 32 queries of one batch. Key tiles of 64, D chunked by 128.
// Thread (kk = tid&15, qq = tid>>4) owns scores s[2][4] (q in {qq,qq+16},
// keys kk+16j) and O[2][32] (d = kk+16*jj). LDS = 59.4 KB -> 2 blocks/CU.
// Grid: (64, 16)
// ---------------------------------------------------------------------------
#define QT 32
#define KT 64
#define DC 128

__global__ __launch_bounds__(256) void attn(
    const float* __restrict__ Q, const float* __restrict__ K,
    const float* __restrict__ V, float* __restrict__ Y)
{
    __shared__ float Qc[QT][DC + 4];    // rows 528 B: 16B-aligned, 2-way banks
    __shared__ float KVc[KT][DC + 4];
    __shared__ float Ps[QT][KT + 4];

    const int tid = threadIdx.x;
    const int kk = tid & 15;
    const int qq = tid >> 4;
    const int b = blockIdx.y;
    const int q0 = blockIdx.x * QT;

    const float* Qp = Q + ((size_t)b * SS + q0) * DKQ;
    const float* Kp = K + (size_t)b * SS * DKQ;
    const float* Vp = V + (size_t)b * SS * DVV;

    float O[2][32];
#pragma unroll
    for (int qi = 0; qi < 2; ++qi)
#pragma unroll
        for (int jj = 0; jj < 32; ++jj) O[qi][jj] = 0.f;

    float m_pr[2] = {-1e30f, -1e30f};
    float l_run[2] = {0.f, 0.f};

    for (int kb = 0; kb < SS; kb += KT) {
        float s[2][4] = {};

        // ---- scores: S = Q Kt over D in chunks of 128 ----
        for (int dc = 0; dc < DKQ; dc += DC) {
#pragma unroll
            for (int i = 0; i < 4; ++i) {   // Q chunk 32x128
                int f = tid + i * 256;
                int row = f >> 5, c4 = f & 31;
                float4 t4 = *(const float4*)&Qp[(size_t)row * DKQ + dc + c4 * 4];
                Qc[row][c4 * 4 + 0] = t4.x; Qc[row][c4 * 4 + 1] = t4.y;
                Qc[row][c4 * 4 + 2] = t4.z; Qc[row][c4 * 4 + 3] = t4.w;
            }
#pragma unroll
            for (int i = 0; i < 8; ++i) {   // K chunk 64x128
                int f = tid + i * 256;
                int row = f >> 5, c4 = f & 31;
                float4 t4 = *(const float4*)&Kp[(size_t)(kb + row) * DKQ + dc + c4 * 4];
                KVc[row][c4 * 4 + 0] = t4.x; KVc[row][c4 * 4 + 1] = t4.y;
                KVc[row][c4 * 4 + 2] = t4.z; KVc[row][c4 * 4 + 3] = t4.w;
            }
            __syncthreads();
#pragma unroll 4
            for (int d = 0; d < DC; ++d) {
                float qv0 = Qc[qq][d];
                float qv1 = Qc[qq + 16][d];
#pragma unroll
                for (int j = 0; j < 4; ++j) {
                    float kv = KVc[kk + 16 * j][d];
                    s[0][j] += qv0 * kv;
                    s[1][j] += qv1 * kv;
                }
            }
            __syncthreads();
        }

        // ---- online softmax update ----
#pragma unroll
        for (int qi = 0; qi < 2; ++qi) {
            float mloc = fmaxf(fmaxf(s[qi][0], s[qi][1]), fmaxf(s[qi][2], s[qi][3]));
#pragma unroll
            for (int off = 1; off < 16; off <<= 1)
                mloc = fmaxf(mloc, __shfl_xor(mloc, off, 64));
            float mnew = fmaxf(m_pr[qi], mloc);
            float p0 = __expf(s[qi][0] - mnew);
            float p1 = __expf(s[qi][1] - mnew);
            float p2 = __expf(s[qi][2] - mnew);
            float p3 = __expf(s[qi][3] - mnew);
            float rs = p0 + p1 + p2 + p3;
#pragma unroll
            for (int off = 1; off < 16; off <<= 1)
                rs += __shfl_xor(rs, off, 64);
            float alpha = __expf(m_pr[qi] - mnew);
            l_run[qi] = l_run[qi] * alpha + rs;
            m_pr[qi] = mnew;
#pragma unroll
            for (int jj = 0; jj < 32; ++jj) O[qi][jj] *= alpha;
            Ps[qq + 16 * qi][kk + 0]  = p0;
            Ps[qq + 16 * qi][kk + 16] = p1;
            Ps[qq + 16 * qi][kk + 32] = p2;
            Ps[qq + 16 * qi][kk + 48] = p3;
        }
        __syncthreads();

        // ---- O += P V over D in chunks of 128 ----
        for (int dc = 0; dc < DVV; dc += DC) {
#pragma unroll
            for (int i = 0; i < 8; ++i) {   // V chunk 64x128 (reuses KVc)
                int f = tid + i * 256;
                int row = f >> 5, c4 = f & 31;
                float4 t4 = *(const float4*)&Vp[(size_t)(kb + row) * DVV + dc + c4 * 4];
                KVc[row][c4 * 4 + 0] = t4.x; KVc[row][c4 * 4 + 1] = t4.y;
                KVc[row][c4 * 4 + 2] = t4.z; KVc[row][c4 * 4 + 3] = t4.w;
            }
            __syncthreads();
            const int jj0 = dc >> 4;
#pragma unroll 4
            for (int key = 0; key < KT; ++key) {
                float pa = Ps[qq][key];
                float pb = Ps[qq + 16][key];
#pragma unroll
                for (int j8 = 0; j8 < 8; ++j8) {
                    float vv = KVc[key][kk + 16 * j8];
                    O[0][jj0 + j8] += pa * vv;
                    O[1][jj0 + j8] += pb * vv;
                }
            }
            __syncthreads();
        }
    }

    // ---- epilogue: normalize and store ----
#pragma unroll
    for (int qi = 0; qi < 2; ++qi) {
        float inv = 1.0f / l_run[qi];
        size_t rowoff = ((size_t)b * SS + q0 + qq + 16 * qi) * DVV;
#pragma unroll
        for (int jj = 0; jj < 32; ++jj)
            Y[rowoff + kk + 16 * jj] = O[qi][jj] * inv;
    }
}

// ---------------------------------------------------------------------------
// Host launcher
// Workspace layout (floats): Wk2(131072) | Wq2(131072) | Wv2(131072) |
//                            Q(16.77M) | K(16.77M) | V(16.77M)  = 202.9 MB
// ---------------------------------------------------------------------------
extern "C" void kernel_launch(void* const* d_in, const int* in_sizes, int n_in,
                              void* d_out, int out_size, void* d_ws, size_t ws_size,
                              hipStream_t stream)
{
    const float* x  = (const float*)d_in[0];
    const float* We = (const float*)d_in[1];
    const float* Wk = (const float*)d_in[2];
    const float* Wq = (const float*)d_in[3];
    const float* Wv = (const float*)d_in[4];
    float* out = (float*)d_out;

    float* ws = (float*)d_ws;
    const size_t WSZ = 256 * 512;             // 131072
    const size_t MSZ = (size_t)BB * SS * 512; // 16777216
    float* Wk2 = ws;
    float* Wq2 = ws + WSZ;
    float* Wv2 = ws + 2 * WSZ;
    float* Qb  = ws + 3 * WSZ;
    float* Kb  = Qb + MSZ;
    float* Vb  = Kb + MSZ;

    // 1) fuse weights: W' = W_embed @ W
    fuse_weights<<<dim3(3 * WSZ / 256), dim3(256), 0, stream>>>(
        We, Wk, Wq, Wv, Wk2, Wq2, Wv2);

    // 2) projections: {K,Q,V} = x @ W'
    qkv_gemm<<<dim3(512 / 64, (BB * SS) / 64, 3), dim3(256), 0, stream>>>(
        x, Wk2, Wq2, Wv2, Kb, Qb, Vb);

    // 3) attention
    attn<<<dim3(SS / QT, BB), dim3(256), 0, stream>>>(Qb, Kb, Vb, out);
}

// Round 2
// 1122.983 us; speedup vs baseline: 2.8396x; 2.8396x over previous
//
#include <hip/hip_runtime.h>
#include <math.h>

// Problem dims (fixed)
#define BB   16
#define SS   2048
#define DIN  256
#define DEMB 512
#define DKQ  512
#define DVV  512

typedef _Float16 f16;
typedef _Float16 half8  __attribute__((ext_vector_type(8)));
typedef _Float16 f16x4  __attribute__((ext_vector_type(4)));
typedef float    f32x4  __attribute__((ext_vector_type(4)));
typedef float    f32x16 __attribute__((ext_vector_type(16)));

#define GLOAD_LDS16(gp, lp)                                                        \
  __builtin_amdgcn_global_load_lds(                                                \
      (const __attribute__((address_space(1))) unsigned int*)(gp),                 \
      (__attribute__((address_space(3))) unsigned int*)(lp), 16, 0, 0)

// ---------------------------------------------------------------------------
// Kernel 1: fuse weights  W'{k,q,v} = W_embed @ W_{k,q,v}   [256 x 512] (fp32)
// ---------------------------------------------------------------------------
__global__ __launch_bounds__(256) void fuse_weights(
    const float* __restrict__ We, const float* __restrict__ Wk,
    const float* __restrict__ Wq, const float* __restrict__ Wv,
    float* __restrict__ Wk2, float* __restrict__ Wq2, float* __restrict__ Wv2)
{
    int idx = blockIdx.x * 256 + threadIdx.x;
    int n = idx & 511;
    int m = (idx >> 9) & 255;
    int w = idx >> 17;
    const float* Wsrc = (w == 0) ? Wk : (w == 1) ? Wq : Wv;
    float* Wdst       = (w == 0) ? Wk2 : (w == 1) ? Wq2 : Wv2;
    float sum = 0.f;
#pragma unroll 8
    for (int kk = 0; kk < DEMB; ++kk)
        sum += We[m * DEMB + kk] * Wsrc[kk * 512 + n];
    Wdst[m * 512 + n] = sum;
}

// ---------------------------------------------------------------------------
// Kernel 2: projections {K,Q,V} = X @ W' (fp32 math), epilogue emits fp16:
//   z=0: Kh fp16 [row][512]
//   z=1: Qh,Ql fp16 split [row][512]   (Q = Qh + Ql exactly at fp16+fp16)
//   z=2: Vt fp16 transposed [b][dv][2048 keys]
// ---------------------------------------------------------------------------
__global__ __launch_bounds__(256) void qkv_gemm(
    const float* __restrict__ X,
    const float* __restrict__ Wk2, const float* __restrict__ Wq2,
    const float* __restrict__ Wv2,
    f16* __restrict__ Kh, f16* __restrict__ Qh, f16* __restrict__ Ql,
    f16* __restrict__ Vt)
{
    const int z = blockIdx.z;
    const float* Wp = (z == 0) ? Wk2 : (z == 1) ? Wq2 : Wv2;

    __shared__ float As[64][17];
    __shared__ float Bs[16][65];

    const int tid = threadIdx.x;
    const int tx = tid & 15, ty = tid >> 4;
    const int m0 = blockIdx.y * 64, n0 = blockIdx.x * 64;

    float c[4][4] = {};

    for (int k0 = 0; k0 < DIN; k0 += 16) {
        {
            int row = tid >> 2, c4 = tid & 3;
            float4 a = *(const float4*)&X[(size_t)(m0 + row) * DIN + k0 + c4 * 4];
            As[row][c4 * 4 + 0] = a.x; As[row][c4 * 4 + 1] = a.y;
            As[row][c4 * 4 + 2] = a.z; As[row][c4 * 4 + 3] = a.w;
        }
        {
            int row = tid >> 4, c4 = tid & 15;
            float4 b = *(const float4*)&Wp[(size_t)(k0 + row) * 512 + n0 + c4 * 4];
            Bs[row][c4 * 4 + 0] = b.x; Bs[row][c4 * 4 + 1] = b.y;
            Bs[row][c4 * 4 + 2] = b.z; Bs[row][c4 * 4 + 3] = b.w;
        }
        __syncthreads();
#pragma unroll
        for (int kk = 0; kk < 16; ++kk) {
            float a0 = As[ty * 4 + 0][kk], a1 = As[ty * 4 + 1][kk];
            float a2 = As[ty * 4 + 2][kk], a3 = As[ty * 4 + 3][kk];
            float b0 = Bs[kk][tx * 4 + 0], b1 = Bs[kk][tx * 4 + 1];
            float b2 = Bs[kk][tx * 4 + 2], b3 = Bs[kk][tx * 4 + 3];
            c[0][0] += a0 * b0; c[0][1] += a0 * b1; c[0][2] += a0 * b2; c[0][3] += a0 * b3;
            c[1][0] += a1 * b0; c[1][1] += a1 * b1; c[1][2] += a1 * b2; c[1][3] += a1 * b3;
            c[2][0] += a2 * b0; c[2][1] += a2 * b1; c[2][2] += a2 * b2; c[2][3] += a2 * b3;
            c[3][0] += a3 * b0; c[3][1] += a3 * b1; c[3][2] += a3 * b2; c[3][3] += a3 * b3;
        }
        __syncthreads();
    }

    if (z == 0) {
#pragma unroll
        for (int i = 0; i < 4; ++i) {
            int m = m0 + ty * 4 + i;
            f16x4 h;
#pragma unroll
            for (int j = 0; j < 4; ++j) h[j] = (f16)c[i][j];
            *(f16x4*)&Kh[(size_t)m * 512 + n0 + tx * 4] = h;
        }
    } else if (z == 1) {
#pragma unroll
        for (int i = 0; i < 4; ++i) {
            int m = m0 + ty * 4 + i;
            f16x4 h, l;
#pragma unroll
            for (int j = 0; j < 4; ++j) {
                f16 hv = (f16)c[i][j];
                h[j] = hv;
                l[j] = (f16)(c[i][j] - (float)hv);
            }
            *(f16x4*)&Qh[(size_t)m * 512 + n0 + tx * 4] = h;
            *(f16x4*)&Ql[(size_t)m * 512 + n0 + tx * 4] = l;
        }
    } else {
#pragma unroll
        for (int i = 0; i < 4; ++i) {
            int m = m0 + ty * 4 + i;
            int bb = m >> 11, key = m & 2047;
#pragma unroll
            for (int j = 0; j < 4; ++j)
                Vt[((size_t)bb * 512 + n0 + tx * 4 + j) * 2048 + key] = (f16)c[i][j];
        }
    }
}

// ---------------------------------------------------------------------------
// Kernel 3: MFMA flash attention (fp16 2-term scores, fp16 PV)
// Block: 4 waves, q-tile 64, K-tile 64 keys.
//  Scores: wave w owns q rows 16w..16w+15, all 64 keys; 16x16x32_f16.
//          Qh/Ql A-frags resident in regs; Kh staged to LDS (64 KB, swizzled).
//  PV: wave w owns q-half (w>>1) x dv-half (w&1); 32x32x16_f16; Vt staged
//          to LDS (64 KB, swizzled); P via LDS (fp16, 8 KB, swizzled).
// 2 barriers per K-tile; staging overlaps the opposite phase's compute.
// LDS total ~140 KB -> 1 block/CU. Grid (32, 16).
// ---------------------------------------------------------------------------
#define LK 0        // Kh tile: 64 keys x 512 d (shorts)  = 32768 shorts
#define LV 32768    // Vt tile: 512 dv x 64 keys          = 32768 shorts
#define LP 65536    // P: 64 q x 64 keys                  = 4096 shorts
#define LA 69632    // alpha[64] floats                   = 128 shorts
#define LL 69760    // l[64] floats                       = 128 shorts
#define LTOT 69888  // 139776 bytes

__global__ __launch_bounds__(256, 1) void attn2(
    const f16* __restrict__ Qh, const f16* __restrict__ Ql,
    const f16* __restrict__ Kh, const f16* __restrict__ Vt,
    float* __restrict__ Y)
{
    __shared__ __align__(16) short sm[LTOT];

    const int tid  = threadIdx.x;
    const int lane = tid & 63;
    const int w    = tid >> 6;
    const int b    = blockIdx.y;
    const int q0   = blockIdx.x * 64;
    const int l15  = lane & 15;
    const int quad = lane >> 4;
    const int l31  = lane & 31;
    const int lhi  = lane >> 5;
    const int qhalf = w >> 1, dvhalf = w & 1;

    const f16* Khb = Kh + (size_t)b * SS * 512;
    const f16* Vtb = Vt + (size_t)b * 512 * (size_t)SS;

    // ---- Q fragments (resident): wave w, q rows q0+16w .. +15 ----
    half8 qh[16], ql[16];
    {
        const half8* qhp = (const half8*)(Qh + ((size_t)(b * SS + q0 + w * 16 + l15)) * 512);
        const half8* qlp = (const half8*)(Ql + ((size_t)(b * SS + q0 + w * 16 + l15)) * 512);
#pragma unroll
        for (int ks = 0; ks < 16; ++ks) {
            qh[ks] = qhp[ks * 4 + quad];
            ql[ks] = qlp[ks * 4 + quad];
        }
    }

    f32x16 O[8];
#pragma unroll
    for (int n = 0; n < 8; ++n)
#pragma unroll
        for (int r = 0; r < 16; ++r) O[n][r] = 0.f;

    float m_pr[4] = {-1e30f, -1e30f, -1e30f, -1e30f};
    float l_r[4]  = {0.f, 0.f, 0.f, 0.f};

    // ---- staging helpers (inlined lambdas) ----
    auto stage_K = [&](int kb) {
#pragma unroll
        for (int i = 0; i < 16; ++i) {
            int key = w * 16 + i;
            const f16* g = Khb + ((size_t)(kb + key)) * 512 + ((lane ^ (key & 15)) << 3);
            GLOAD_LDS16(g, sm + LK + key * 512);
        }
    };
    auto stage_V = [&](int kb) {
#pragma unroll
        for (int i = 0; i < 16; ++i) {
            int dvb = w * 128 + i * 8;
            int dv  = dvb + (lane >> 3);
            const f16* g = Vtb + (size_t)dv * SS + kb + (((lane & 7) ^ (dv & 7)) << 3);
            GLOAD_LDS16(g, sm + LV + dvb * 64);
        }
    };

    float* aptr = (float*)(sm + LA);
    float* lptr = (float*)(sm + LL);

    stage_K(0);

    for (int t = 0; t < 32; ++t) {
        const int kb = t * 64;
        __syncthreads();              // K(t) staged; Vbuf free (PV(t-1) done)
        stage_V(kb);                  // overlaps score phase

        // ---- score phase: S = Qh*Kh + Ql*Kh ----
        f32x4 S[4], T[4];
#pragma unroll
        for (int n = 0; n < 4; ++n) {
            S[n] = (f32x4){0.f, 0.f, 0.f, 0.f};
            T[n] = (f32x4){0.f, 0.f, 0.f, 0.f};
        }
#pragma unroll
        for (int ks = 0; ks < 16; ++ks) {
#pragma unroll
            for (int n = 0; n < 4; ++n) {
                int key = n * 16 + l15;
                int ud  = ks * 4 + quad;
                half8 bf = *(const half8*)(sm + LK + key * 512 + ((ud ^ (key & 15)) << 3));
                S[n] = __builtin_amdgcn_mfma_f32_16x16x32_f16(qh[ks], bf, S[n], 0, 0, 0);
                T[n] = __builtin_amdgcn_mfma_f32_16x16x32_f16(ql[ks], bf, T[n], 0, 0, 0);
            }
        }

        // ---- online softmax (per wave: 16 q rows x 64 keys) ----
        float sf[4][4];
#pragma unroll
        for (int n = 0; n < 4; ++n)
#pragma unroll
            for (int r = 0; r < 4; ++r) sf[n][r] = S[n][r] + T[n][r];

        float mx[4], sum[4], al[4];
#pragma unroll
        for (int r = 0; r < 4; ++r)
            mx[r] = fmaxf(fmaxf(sf[0][r], sf[1][r]), fmaxf(sf[2][r], sf[3][r]));
#pragma unroll
        for (int off = 1; off < 16; off <<= 1)
#pragma unroll
            for (int r = 0; r < 4; ++r)
                mx[r] = fmaxf(mx[r], __shfl_xor(mx[r], off, 64));
#pragma unroll
        for (int r = 0; r < 4; ++r) {
            float mn = fmaxf(m_pr[r], mx[r]);
            al[r] = __expf(m_pr[r] - mn);
            m_pr[r] = mn;
            sum[r] = 0.f;
        }
        // exp + P write (fp16, swizzled rows of 64)
#pragma unroll
        for (int n = 0; n < 4; ++n) {
#pragma unroll
            for (int r = 0; r < 4; ++r) {
                float p = __expf(sf[n][r] - m_pr[r]);
                sum[r] += p;
                int q   = w * 16 + quad * 4 + r;
                int key = n * 16 + l15;
                *(f16*)(sm + LP + q * 64 + (((key >> 3) ^ (q & 7)) << 3) + (key & 7)) = (f16)p;
            }
        }
#pragma unroll
        for (int off = 1; off < 16; off <<= 1)
#pragma unroll
            for (int r = 0; r < 4; ++r)
                sum[r] += __shfl_xor(sum[r], off, 64);
#pragma unroll
        for (int r = 0; r < 4; ++r)
            l_r[r] = l_r[r] * al[r] + sum[r];
        if (l15 == 0) {
#pragma unroll
            for (int r = 0; r < 4; ++r) aptr[w * 16 + quad * 4 + r] = al[r];
        }

        __syncthreads();              // V(t), P, alpha ready; Kbuf reads done
        if (t < 31) stage_K(kb + 64); // overlaps PV phase

        // ---- PV phase: O += P * V (32x32x16) ----
        half8 pA[4];
#pragma unroll
        for (int ks = 0; ks < 4; ++ks) {
            int q  = qhalf * 32 + l31;
            int uk = ks * 2 + lhi;
            pA[ks] = *(const half8*)(sm + LP + q * 64 + ((uk ^ (q & 7)) << 3));
        }
        // rescale O by alpha
        float av[16];
#pragma unroll
        for (int r = 0; r < 16; ++r) {
            int row = (r & 3) + ((r >> 2) << 3) + (lhi << 2);
            av[r] = aptr[qhalf * 32 + row];
        }
#pragma unroll
        for (int n = 0; n < 8; ++n)
#pragma unroll
            for (int r = 0; r < 16; ++r) O[n][r] *= av[r];

#pragma unroll
        for (int ks = 0; ks < 4; ++ks) {
#pragma unroll
            for (int n = 0; n < 8; ++n) {
                int dv = dvhalf * 256 + n * 32 + l31;
                int uk = ks * 2 + lhi;
                half8 bf = *(const half8*)(sm + LV + dv * 64 + ((uk ^ (dv & 7)) << 3));
                O[n] = __builtin_amdgcn_mfma_f32_32x32x16_f16(pA[ks], bf, O[n], 0, 0, 0);
            }
        }
    }

    // ---- epilogue: O /= l, store ----
    if (l15 == 0) {
#pragma unroll
        for (int r = 0; r < 4; ++r) lptr[w * 16 + quad * 4 + r] = l_r[r];
    }
    __syncthreads();
    float linv[16];
#pragma unroll
    for (int r = 0; r < 16; ++r) {
        int row = (r & 3) + ((r >> 2) << 3) + (lhi << 2);
        linv[r] = 1.0f / lptr[qhalf * 32 + row];
    }
#pragma unroll
    for (int n = 0; n < 8; ++n) {
#pragma unroll
        for (int r = 0; r < 16; ++r) {
            int row = (r & 3) + ((r >> 2) << 3) + (lhi << 2);
            Y[((size_t)(b * SS + q0 + qhalf * 32 + row)) * 512 + dvhalf * 256 + n * 32 + l31] =
                O[n][r] * linv[r];
        }
    }
}

// ---------------------------------------------------------------------------
// Host launcher
// Workspace: Wk2|Wq2|Wv2 fp32 (1.5 MB) + Qh|Ql|Kh|Vt fp16 (134 MB)
// ---------------------------------------------------------------------------
extern "C" void kernel_launch(void* const* d_in, const int* in_sizes, int n_in,
                              void* d_out, int out_size, void* d_ws, size_t ws_size,
                              hipStream_t stream)
{
    const float* x  = (const float*)d_in[0];
    const float* We = (const float*)d_in[1];
    const float* Wk = (const float*)d_in[2];
    const float* Wq = (const float*)d_in[3];
    const float* Wv = (const float*)d_in[4];
    float* out = (float*)d_out;

    const size_t WSZ = 256 * 512;
    const size_t MSZ = (size_t)BB * SS * 512;

    float* Wk2 = (float*)d_ws;
    float* Wq2 = Wk2 + WSZ;
    float* Wv2 = Wq2 + WSZ;
    f16* Qh = (f16*)(Wv2 + WSZ);
    f16* Ql = Qh + MSZ;
    f16* Kh = Ql + MSZ;
    f16* Vt = Kh + MSZ;

    fuse_weights<<<dim3(3 * WSZ / 256), dim3(256), 0, stream>>>(
        We, Wk, Wq, Wv, Wk2, Wq2, Wv2);

    qkv_gemm<<<dim3(512 / 64, (BB * SS) / 64, 3), dim3(256), 0, stream>>>(
        x, Wk2, Wq2, Wv2, Kh, Qh, Ql, Vt);

    attn2<<<dim3(SS / 64, BB), dim3(256), 0, stream>>>(Qh, Ql, Kh, Vt, out);
}

// Round 3
// 1083.099 us; speedup vs baseline: 2.9442x; 1.0368x over previous
//
#include <hip/hip_runtime.h>
#include <math.h>

// Problem dims (fixed)
#define BB   16
#define SS   2048
#define DIN  256
#define DEMB 512
#define DKQ  512
#define DVV  512

typedef _Float16 f16;
typedef _Float16 half8  __attribute__((ext_vector_type(8)));
typedef _Float16 f16x4  __attribute__((ext_vector_type(4)));
typedef float    f32x4  __attribute__((ext_vector_type(4)));
typedef float    f32x16 __attribute__((ext_vector_type(16)));

#define GLOAD_LDS16(gp, lp)                                                        \
  __builtin_amdgcn_global_load_lds(                                                \
      (const __attribute__((address_space(1))) unsigned int*)(gp),                 \
      (__attribute__((address_space(3))) unsigned int*)(lp), 16, 0, 0)

// ---------------------------------------------------------------------------
// Kernel 0: split x (fp32) -> Xh, Xl (fp16 pair, exact to ~2^-22)
// ---------------------------------------------------------------------------
__global__ __launch_bounds__(256) void prep_x(
    const float* __restrict__ x, f16* __restrict__ Xh, f16* __restrict__ Xl)
{
    int idx = blockIdx.x * 256 + threadIdx.x;     // 2,097,152 float4 groups
    float4 v = ((const float4*)x)[idx];
    f16x4 h, l;
    h.x = (f16)v.x; l.x = (f16)(v.x - (float)h.x);
    h.y = (f16)v.y; l.y = (f16)(v.y - (float)h.y);
    h.z = (f16)v.z; l.z = (f16)(v.z - (float)h.z);
    h.w = (f16)v.w; l.w = (f16)(v.w - (float)h.w);
    ((f16x4*)Xh)[idx] = h;
    ((f16x4*)Xl)[idx] = l;
}

// ---------------------------------------------------------------------------
// Kernel 1: fuse weights W' = W_embed @ W (fp32 math), output TRANSPOSED
// fp16 split:  Wth/Wtl [z][n=512][k=256]
// ---------------------------------------------------------------------------
__global__ __launch_bounds__(256) void fuse_weights(
    const float* __restrict__ We, const float* __restrict__ Wk,
    const float* __restrict__ Wq, const float* __restrict__ Wv,
    f16* __restrict__ Wth, f16* __restrict__ Wtl)
{
    int idx = blockIdx.x * 256 + threadIdx.x;
    int n = idx & 511;
    int m = (idx >> 9) & 255;
    int z = idx >> 17;
    const float* Wsrc = (z == 0) ? Wk : (z == 1) ? Wq : Wv;
    float sum = 0.f;
#pragma unroll 8
    for (int kk = 0; kk < DEMB; ++kk)
        sum += We[m * DEMB + kk] * Wsrc[kk * 512 + n];
    f16 h = (f16)sum;
    f16 l = (f16)(sum - (float)h);
    Wth[(size_t)z * 131072 + n * 256 + m] = h;
    Wtl[(size_t)z * 131072 + n * 256 + m] = l;
}

// ---------------------------------------------------------------------------
// Kernel 2: MFMA projections, 3-term fp16 split (Ah*Bh + Al*Bh + Ah*Bl).
// Tile 128x128, K-chunk 64, 4 waves (2x2 of 64x64). global_load_lds staging.
//   z=0 -> Kh [row][512]; z=1 -> Qh [row][512]; z=2 -> Vt [b][dv][2048]
// Epilogue routes C through LDS for coalesced fp16 stores (incl. transpose).
// ---------------------------------------------------------------------------
#define QAH 0
#define QAL 8192
#define QBH 16384
#define QBL 24576

__global__ __launch_bounds__(256) void qkv_gemm(
    const f16* __restrict__ Xh, const f16* __restrict__ Xl,
    const f16* __restrict__ Wth, const f16* __restrict__ Wtl,
    f16* __restrict__ Kh, f16* __restrict__ Qh, f16* __restrict__ Vt)
{
    __shared__ __align__(16) short smq[32768];   // 64 KB

    const int tid  = threadIdx.x;
    const int lane = tid & 63;
    const int w    = tid >> 6;
    const int z    = blockIdx.z;
    const int m0   = blockIdx.y * 128;
    const int n0   = blockIdx.x * 128;
    const int l15  = lane & 15;
    const int quad = lane >> 4;
    const int wm   = (w >> 1) * 64, wn = (w & 1) * 64;

    const f16* Bh = Wth + (size_t)z * 131072;
    const f16* Bl = Wtl + (size_t)z * 131072;

    f32x4 acc[4][4];
#pragma unroll
    for (int i = 0; i < 4; ++i)
#pragma unroll
        for (int j = 0; j < 4; ++j) acc[i][j] = (f32x4){0.f, 0.f, 0.f, 0.f};

    const int lrow = lane >> 3;          // 0..7 rows per 1KB instr
    const int lswz = ((lane & 7) ^ (lrow & 7)) << 3;

    for (int c = 0; c < 4; ++c) {
        const int k0 = c * 64;
        // stage Ah/Al (X rows m0..m0+127) and Bh/Bl (Wt rows n0..n0+127)
#pragma unroll
        for (int i = 0; i < 4; ++i) {
            int r0 = w * 32 + i * 8;
            int row = r0 + lrow;
            GLOAD_LDS16(Xh + (size_t)(m0 + row) * 256 + k0 + lswz, smq + QAH + r0 * 64);
            GLOAD_LDS16(Xl + (size_t)(m0 + row) * 256 + k0 + lswz, smq + QAL + r0 * 64);
            GLOAD_LDS16(Bh + (size_t)(n0 + row) * 256 + k0 + lswz, smq + QBH + r0 * 64);
            GLOAD_LDS16(Bl + (size_t)(n0 + row) * 256 + k0 + lswz, smq + QBL + r0 * 64);
        }
        __syncthreads();
#pragma unroll
        for (int ks = 0; ks < 2; ++ks) {
            const int kg = ks * 4 + quad;
            const int rsw = (kg ^ (l15 & 7)) << 3;
            half8 ah[4], al[4], bh[4], bl[4];
#pragma unroll
            for (int i = 0; i < 4; ++i) {
                int m = wm + i * 16 + l15;
                int n = wn + i * 16 + l15;
                ah[i] = *(const half8*)(smq + QAH + m * 64 + rsw);
                al[i] = *(const half8*)(smq + QAL + m * 64 + rsw);
                bh[i] = *(const half8*)(smq + QBH + n * 64 + rsw);
                bl[i] = *(const half8*)(smq + QBL + n * 64 + rsw);
            }
#pragma unroll
            for (int mi = 0; mi < 4; ++mi)
#pragma unroll
                for (int ni = 0; ni < 4; ++ni) {
                    acc[mi][ni] = __builtin_amdgcn_mfma_f32_16x16x32_f16(ah[mi], bh[ni], acc[mi][ni], 0, 0, 0);
                    acc[mi][ni] = __builtin_amdgcn_mfma_f32_16x16x32_f16(al[mi], bh[ni], acc[mi][ni], 0, 0, 0);
                    acc[mi][ni] = __builtin_amdgcn_mfma_f32_16x16x32_f16(ah[mi], bl[ni], acc[mi][ni], 0, 0, 0);
                }
        }
        __syncthreads();
    }

    // ---- epilogue via LDS (stride 136 shorts = 272B, 16B-aligned) ----
    if (z < 2) {
#pragma unroll
        for (int mi = 0; mi < 4; ++mi)
#pragma unroll
            for (int ni = 0; ni < 4; ++ni)
#pragma unroll
                for (int r = 0; r < 4; ++r)
                    *(f16*)(smq + (wm + mi * 16 + quad * 4 + r) * 136 + wn + ni * 16 + l15) =
                        (f16)acc[mi][ni][r];
        __syncthreads();
        f16* Out = (z == 0) ? Kh : Qh;
        int cg = tid & 15;
#pragma unroll
        for (int j = 0; j < 8; ++j) {
            int row = j * 16 + (tid >> 4);
            half8 v = *(const half8*)(smq + row * 136 + cg * 8);
            *(half8*)&Out[(size_t)(m0 + row) * 512 + n0 + cg * 8] = v;
        }
    } else {
        // transpose: LDS[col n][row m]
#pragma unroll
        for (int mi = 0; mi < 4; ++mi)
#pragma unroll
            for (int ni = 0; ni < 4; ++ni)
#pragma unroll
                for (int r = 0; r < 4; ++r)
                    *(f16*)(smq + (wn + ni * 16 + l15) * 136 + wm + mi * 16 + quad * 4 + r) =
                        (f16)acc[mi][ni][r];
        __syncthreads();
        int bb = m0 >> 11, key0 = m0 & 2047;
        int cg = tid & 15;
#pragma unroll
        for (int j = 0; j < 8; ++j) {
            int dvr = j * 16 + (tid >> 4);
            half8 v = *(const half8*)(smq + dvr * 136 + cg * 8);
            *(half8*)&Vt[((size_t)bb * 512 + n0 + dvr) * 2048 + key0 + cg * 8] = v;
        }
    }
}

// ---------------------------------------------------------------------------
// Kernel 3: MFMA flash attention, 1-term fp16 scores + fp16 PV.
// Block: 4 waves, q-tile 64, K-tile 32 keys (64 tiles). LDS 75.3 KB ->
// 2 blocks/CU (2 waves/SIMD). Persistent VGPR: qh 64 + O 128 = 192.
// O-rescale skipped when no q-row's running max changed (block-wide flags).
// ---------------------------------------------------------------------------
#define LK 0        // K tile: 32 keys x 512 d            = 16384 shorts
#define LV 16384    // Vt tile: 512 dv x 32 keys          = 16384 shorts
#define LP 32768    // P: 64 q x stride 72                =  4608 shorts
#define LA 37376    // alpha[64] floats                   =   128 shorts
#define LL 37504    // l[64] floats                       =   128 shorts
#define LF 37632    // flags[4] ints                      =     8 shorts
#define LTOT 37648  // 75296 bytes

__global__ __launch_bounds__(256, 2) void attn2(
    const f16* __restrict__ Qh, const f16* __restrict__ Kh,
    const f16* __restrict__ Vt, float* __restrict__ Y)
{
    __shared__ __align__(16) short sm[LTOT];

    const int tid  = threadIdx.x;
    const int lane = tid & 63;
    const int w    = tid >> 6;
    const int b    = blockIdx.y;
    const int q0   = blockIdx.x * 64;
    const int l15  = lane & 15;
    const int quad = lane >> 4;
    const int l31  = lane & 31;
    const int lhi  = lane >> 5;
    const int qhalf = w >> 1, dvhalf = w & 1;

    const f16* Khb = Kh + (size_t)b * SS * 512;
    const f16* Vtb = Vt + (size_t)b * 512 * (size_t)SS;

    // ---- Q fragments (resident): wave w, q rows q0+16w .. +15 ----
    half8 qh[16];
    {
        const half8* qhp = (const half8*)(Qh + ((size_t)(b * SS + q0 + w * 16 + l15)) * 512);
#pragma unroll
        for (int ks = 0; ks < 16; ++ks) qh[ks] = qhp[ks * 4 + quad];
    }

    f32x16 O[8];
#pragma unroll
    for (int n = 0; n < 8; ++n)
#pragma unroll
        for (int r = 0; r < 16; ++r) O[n][r] = 0.f;

    float m_pr[4] = {-1e30f, -1e30f, -1e30f, -1e30f};
    float l_r[4]  = {0.f, 0.f, 0.f, 0.f};

    auto stage_K = [&](int kb) {
#pragma unroll
        for (int i = 0; i < 8; ++i) {
            int key = w * 8 + i;
            const f16* g = Khb + ((size_t)(kb + key)) * 512 + ((lane ^ (key & 15)) << 3);
            GLOAD_LDS16(g, sm + LK + key * 512);
        }
    };
    const int vswz = ((lane & 3) ^ ((lane >> 2) & 3)) << 3;
    auto stage_V = [&](int kb) {
#pragma unroll
        for (int i = 0; i < 8; ++i) {
            int dvb = w * 128 + i * 16;
            int dv  = dvb + (lane >> 2);
            const f16* g = Vtb + (size_t)dv * SS + kb + vswz;
            GLOAD_LDS16(g, sm + LV + dvb * 32);
        }
    };

    float* aptr = (float*)(sm + LA);
    float* lptr = (float*)(sm + LL);
    int*   fptr = (int*)(sm + LF);

    stage_K(0);

    for (int t = 0; t < 64; ++t) {
        const int kb = t * 32;
        __syncthreads();              // K(t) staged; V buffer free
        stage_V(kb);                  // overlaps score phase

        // ---- scores: S = Qh * Kh^T (16x16x32), 16 q x 32 keys per wave ----
        f32x4 S[2];
        S[0] = (f32x4){0.f, 0.f, 0.f, 0.f};
        S[1] = (f32x4){0.f, 0.f, 0.f, 0.f};
#pragma unroll
        for (int ks = 0; ks < 16; ++ks) {
#pragma unroll
            for (int n = 0; n < 2; ++n) {
                int key = n * 16 + l15;
                int ud  = ks * 4 + quad;
                half8 bf = *(const half8*)(sm + LK + key * 512 + ((ud ^ l15) << 3));
                S[n] = __builtin_amdgcn_mfma_f32_16x16x32_f16(qh[ks], bf, S[n], 0, 0, 0);
            }
        }

        // ---- online softmax ----
        float mx[4], sum[4], al[4];
#pragma unroll
        for (int r = 0; r < 4; ++r) mx[r] = fmaxf(S[0][r], S[1][r]);
#pragma unroll
        for (int off = 1; off < 16; off <<= 1)
#pragma unroll
            for (int r = 0; r < 4; ++r)
                mx[r] = fmaxf(mx[r], __shfl_xor(mx[r], off, 64));
#pragma unroll
        for (int r = 0; r < 4; ++r) {
            float mn = fmaxf(m_pr[r], mx[r]);
            al[r] = __expf(m_pr[r] - mn);
            m_pr[r] = mn;
            sum[r] = 0.f;
        }
#pragma unroll
        for (int n = 0; n < 2; ++n) {
#pragma unroll
            for (int r = 0; r < 4; ++r) {
                float p = __expf(S[n][r] - m_pr[r]);
                sum[r] += p;
                int q   = w * 16 + quad * 4 + r;
                int key = n * 16 + l15;
                *(f16*)(sm + LP + q * 72 + key) = (f16)p;
            }
        }
#pragma unroll
        for (int off = 1; off < 16; off <<= 1)
#pragma unroll
            for (int r = 0; r < 4; ++r)
                sum[r] += __shfl_xor(sum[r], off, 64);
#pragma unroll
        for (int r = 0; r < 4; ++r)
            l_r[r] = l_r[r] * al[r] + sum[r];
        bool any = (al[0] < 1.f) | (al[1] < 1.f) | (al[2] < 1.f) | (al[3] < 1.f);
        unsigned long long bm = __ballot(any);
        if (lane == 0) fptr[w] = (bm != 0ULL) ? 1 : 0;
        if (l15 == 0) {
#pragma unroll
            for (int r = 0; r < 4; ++r) aptr[w * 16 + quad * 4 + r] = al[r];
        }

        __syncthreads();              // V(t), P, alpha, flags ready; K free
        if (t < 63) stage_K(kb + 32); // overlaps PV phase

        // ---- O rescale (skipped when running max unchanged block-half) ----
        if (fptr[2 * qhalf] | fptr[2 * qhalf + 1]) {
            float av[16];
#pragma unroll
            for (int r = 0; r < 16; ++r) {
                int row = (r & 3) + ((r >> 2) << 3) + (lhi << 2);
                av[r] = aptr[qhalf * 32 + row];
            }
#pragma unroll
            for (int n = 0; n < 8; ++n)
#pragma unroll
                for (int r = 0; r < 16; ++r) O[n][r] *= av[r];
        }

        // ---- PV: O += P * V (32x32x16), 32 q x 256 dv per wave ----
        half8 pA[2];
#pragma unroll
        for (int ks = 0; ks < 2; ++ks) {
            int q  = qhalf * 32 + l31;
            int uk = ks * 2 + lhi;
            pA[ks] = *(const half8*)(sm + LP + q * 72 + uk * 8);
        }
#pragma unroll
        for (int ks = 0; ks < 2; ++ks) {
#pragma unroll
            for (int n = 0; n < 8; ++n) {
                int dv = dvhalf * 256 + n * 32 + l31;
                int uk = ks * 2 + lhi;
                half8 bf = *(const half8*)(sm + LV + dv * 32 + ((uk ^ (lane & 3)) << 3));
                O[n] = __builtin_amdgcn_mfma_f32_32x32x16_f16(pA[ks], bf, O[n], 0, 0, 0);
            }
        }
    }

    // ---- epilogue: O /= l, store ----
    if (l15 == 0) {
#pragma unroll
        for (int r = 0; r < 4; ++r) lptr[w * 16 + quad * 4 + r] = l_r[r];
    }
    __syncthreads();
    float linv[16];
#pragma unroll
    for (int r = 0; r < 16; ++r) {
        int row = (r & 3) + ((r >> 2) << 3) + (lhi << 2);
        linv[r] = 1.0f / lptr[qhalf * 32 + row];
    }
#pragma unroll
    for (int n = 0; n < 8; ++n) {
#pragma unroll
        for (int r = 0; r < 16; ++r) {
            int row = (r & 3) + ((r >> 2) << 3) + (lhi << 2);
            Y[((size_t)(b * SS + q0 + qhalf * 32 + row)) * 512 + dvhalf * 256 + n * 32 + l31] =
                O[n][r] * linv[r];
        }
    }
}

// ---------------------------------------------------------------------------
// Host launcher
// Workspace (f16 units): Wth(393216) Wtl(393216) Xh(8388608) Xl(8388608)
//                        Qh(16777216) Kh(16777216) Vt(16777216)  ~136 MB
// ---------------------------------------------------------------------------
extern "C" void kernel_launch(void* const* d_in, const int* in_sizes, int n_in,
                              void* d_out, int out_size, void* d_ws, size_t ws_size,
                              hipStream_t stream)
{
    const float* x  = (const float*)d_in[0];
    const float* We = (const float*)d_in[1];
    const float* Wk = (const float*)d_in[2];
    const float* Wq = (const float*)d_in[3];
    const float* Wv = (const float*)d_in[4];
    float* out = (float*)d_out;

    const size_t WSZ = 3 * 256 * 512;          // 393216
    const size_t XSZ = (size_t)BB * SS * DIN;  // 8388608
    const size_t MSZ = (size_t)BB * SS * 512;  // 16777216

    f16* Wth = (f16*)d_ws;
    f16* Wtl = Wth + WSZ;
    f16* Xh  = Wtl + WSZ;
    f16* Xl  = Xh + XSZ;
    f16* Qh  = Xl + XSZ;
    f16* Kh  = Qh + MSZ;
    f16* Vt  = Kh + MSZ;

    prep_x<<<dim3(XSZ / 4 / 256), dim3(256), 0, stream>>>(x, Xh, Xl);

    fuse_weights<<<dim3(1536), dim3(256), 0, stream>>>(We, Wk, Wq, Wv, Wth, Wtl);

    qkv_gemm<<<dim3(4, 256, 3), dim3(256), 0, stream>>>(
        Xh, Xl, Wth, Wtl, Kh, Qh, Vt);

    attn2<<<dim3(SS / 64, BB), dim3(256), 0, stream>>>(Qh, Kh, Vt, out);
}

// Round 4
// 638.394 us; speedup vs baseline: 4.9951x; 1.6966x over previous
//
#include <hip/hip_runtime.h>
#include <math.h>

// Problem dims (fixed)
#define BB   16
#define SS   2048
#define DIN  256
#define DEMB 512
#define DKQ  512
#define DVV  512

typedef _Float16 f16;
typedef _Float16 half8  __attribute__((ext_vector_type(8)));
typedef _Float16 f16x4  __attribute__((ext_vector_type(4)));
typedef float    f32x4  __attribute__((ext_vector_type(4)));
typedef float    f32x16 __attribute__((ext_vector_type(16)));

#define GLOAD_LDS16(gp, lp)                                                        \
  __builtin_amdgcn_global_load_lds(                                                \
      (const __attribute__((address_space(1))) unsigned int*)(gp),                 \
      (__attribute__((address_space(3))) unsigned int*)(lp), 16, 0, 0)

// V slot permute: decorrelates LDS bank-start across dv rows (2-way max)
__device__ __forceinline__ int vperm(int dv) { return (dv ^ (dv >> 2)) & 3; }

// ---------------------------------------------------------------------------
// Kernel 0: split x (fp32) -> Xh, Xl (fp16 pair, exact to ~2^-22)
// ---------------------------------------------------------------------------
__global__ __launch_bounds__(256) void prep_x(
    const float* __restrict__ x, f16* __restrict__ Xh, f16* __restrict__ Xl)
{
    int idx = blockIdx.x * 256 + threadIdx.x;
    float4 v = ((const float4*)x)[idx];
    f16x4 h, l;
    h.x = (f16)v.x; l.x = (f16)(v.x - (float)h.x);
    h.y = (f16)v.y; l.y = (f16)(v.y - (float)h.y);
    h.z = (f16)v.z; l.z = (f16)(v.z - (float)h.z);
    h.w = (f16)v.w; l.w = (f16)(v.w - (float)h.w);
    ((f16x4*)Xh)[idx] = h;
    ((f16x4*)Xl)[idx] = l;
}

// ---------------------------------------------------------------------------
// Kernel 1: fuse weights W' = W_embed @ W (fp32 math), output TRANSPOSED
// fp16 split:  Wth/Wtl [z][n=512][k=256]
// ---------------------------------------------------------------------------
__global__ __launch_bounds__(256) void fuse_weights(
    const float* __restrict__ We, const float* __restrict__ Wk,
    const float* __restrict__ Wq, const float* __restrict__ Wv,
    f16* __restrict__ Wth, f16* __restrict__ Wtl)
{
    int idx = blockIdx.x * 256 + threadIdx.x;
    int n = idx & 511;
    int m = (idx >> 9) & 255;
    int z = idx >> 17;
    const float* Wsrc = (z == 0) ? Wk : (z == 1) ? Wq : Wv;
    float sum = 0.f;
#pragma unroll 8
    for (int kk = 0; kk < DEMB; ++kk)
        sum += We[m * DEMB + kk] * Wsrc[kk * 512 + n];
    f16 h = (f16)sum;
    f16 l = (f16)(sum - (float)h);
    Wth[(size_t)z * 131072 + n * 256 + m] = h;
    Wtl[(size_t)z * 131072 + n * 256 + m] = l;
}

// ---------------------------------------------------------------------------
// Kernel 2: MFMA projections, 3-term fp16 split (Ah*Bh + Al*Bh + Ah*Bl).
// Tile 128x128, K-chunk 64, 4 waves. global_load_lds staging.
//   z=0 -> Kh [row][512]; z=1 -> Qh [row][512];
//   z=2 -> Vt2 [b][tile(64)][dv(512)][32 keys], 16B slots permuted by vperm(dv)
// ---------------------------------------------------------------------------
#define QAH 0
#define QAL 8192
#define QBH 16384
#define QBL 24576

__global__ __launch_bounds__(256) void qkv_gemm(
    const f16* __restrict__ Xh, const f16* __restrict__ Xl,
    const f16* __restrict__ Wth, const f16* __restrict__ Wtl,
    f16* __restrict__ Kh, f16* __restrict__ Qh, f16* __restrict__ Vt2)
{
    __shared__ __align__(16) short smq[32768];   // 64 KB

    const int tid  = threadIdx.x;
    const int lane = tid & 63;
    const int w    = tid >> 6;
    const int z    = blockIdx.z;
    const int m0   = blockIdx.y * 128;
    const int n0   = blockIdx.x * 128;
    const int l15  = lane & 15;
    const int quad = lane >> 4;
    const int wm   = (w >> 1) * 64, wn = (w & 1) * 64;

    const f16* Bh = Wth + (size_t)z * 131072;
    const f16* Bl = Wtl + (size_t)z * 131072;

    f32x4 acc[4][4];
#pragma unroll
    for (int i = 0; i < 4; ++i)
#pragma unroll
        for (int j = 0; j < 4; ++j) acc[i][j] = (f32x4){0.f, 0.f, 0.f, 0.f};

    const int lrow = lane >> 3;
    const int lswz = ((lane & 7) ^ (lrow & 7)) << 3;

    for (int c = 0; c < 4; ++c) {
        const int k0 = c * 64;
#pragma unroll
        for (int i = 0; i < 4; ++i) {
            int r0 = w * 32 + i * 8;
            int row = r0 + lrow;
            GLOAD_LDS16(Xh + (size_t)(m0 + row) * 256 + k0 + lswz, smq + QAH + r0 * 64);
            GLOAD_LDS16(Xl + (size_t)(m0 + row) * 256 + k0 + lswz, smq + QAL + r0 * 64);
            GLOAD_LDS16(Bh + (size_t)(n0 + row) * 256 + k0 + lswz, smq + QBH + r0 * 64);
            GLOAD_LDS16(Bl + (size_t)(n0 + row) * 256 + k0 + lswz, smq + QBL + r0 * 64);
        }
        __syncthreads();
#pragma unroll
        for (int ks = 0; ks < 2; ++ks) {
            const int kg = ks * 4 + quad;
            const int rsw = (kg ^ (l15 & 7)) << 3;
            half8 ah[4], al[4], bh[4], bl[4];
#pragma unroll
            for (int i = 0; i < 4; ++i) {
                int m = wm + i * 16 + l15;
                int n = wn + i * 16 + l15;
                ah[i] = *(const half8*)(smq + QAH + m * 64 + rsw);
                al[i] = *(const half8*)(smq + QAL + m * 64 + rsw);
                bh[i] = *(const half8*)(smq + QBH + n * 64 + rsw);
                bl[i] = *(const half8*)(smq + QBL + n * 64 + rsw);
            }
#pragma unroll
            for (int mi = 0; mi < 4; ++mi)
#pragma unroll
                for (int ni = 0; ni < 4; ++ni) {
                    acc[mi][ni] = __builtin_amdgcn_mfma_f32_16x16x32_f16(ah[mi], bh[ni], acc[mi][ni], 0, 0, 0);
                    acc[mi][ni] = __builtin_amdgcn_mfma_f32_16x16x32_f16(al[mi], bh[ni], acc[mi][ni], 0, 0, 0);
                    acc[mi][ni] = __builtin_amdgcn_mfma_f32_16x16x32_f16(ah[mi], bl[ni], acc[mi][ni], 0, 0, 0);
                }
        }
        __syncthreads();
    }

    // ---- epilogue via LDS (stride 136 shorts) ----
    if (z < 2) {
#pragma unroll
        for (int mi = 0; mi < 4; ++mi)
#pragma unroll
            for (int ni = 0; ni < 4; ++ni)
#pragma unroll
                for (int r = 0; r < 4; ++r)
                    *(f16*)(smq + (wm + mi * 16 + quad * 4 + r) * 136 + wn + ni * 16 + l15) =
                        (f16)acc[mi][ni][r];
        __syncthreads();
        f16* Out = (z == 0) ? Kh : Qh;
        int cg = tid & 15;
#pragma unroll
        for (int j = 0; j < 8; ++j) {
            int row = j * 16 + (tid >> 4);
            half8 v = *(const half8*)(smq + row * 136 + cg * 8);
            *(half8*)&Out[(size_t)(m0 + row) * 512 + n0 + cg * 8] = v;
        }
    } else {
        // transpose in LDS: [dv_local][key_local]
#pragma unroll
        for (int mi = 0; mi < 4; ++mi)
#pragma unroll
            for (int ni = 0; ni < 4; ++ni)
#pragma unroll
                for (int r = 0; r < 4; ++r)
                    *(f16*)(smq + (wn + ni * 16 + l15) * 136 + wm + mi * 16 + quad * 4 + r) =
                        (f16)acc[mi][ni][r];
        __syncthreads();
        int bb = m0 >> 11, kb0 = m0 & 2047;
        int cg = tid & 15;
#pragma unroll
        for (int j = 0; j < 8; ++j) {
            int dvr = j * 16 + (tid >> 4);
            int dv  = n0 + dvr;
            half8 v = *(const half8*)(smq + dvr * 136 + cg * 8);
            int t  = (kb0 >> 5) + (cg >> 2);     // key tile
            int s  = (cg & 3) ^ vperm(dv);       // permuted 16B slot
            *(half8*)&Vt2[(((size_t)bb * 64 + t) * 512 + dv) * 32 + s * 8] = v;
        }
    }
}

// ---------------------------------------------------------------------------
// Kernel 3: MFMA flash attention, 1-term fp16 scores + fp16 PV.
// Block: 4 waves, q-tile 64, K-tile 32 keys (64 tiles). LDS 75.3 KB ->
// 2 blocks/CU. XCD swizzle: all q-blocks of a batch on one XCD so the K/V
// stream stays L2-resident. V staged from tile-major Vt2 (contiguous 32 KB).
// ---------------------------------------------------------------------------
#define LK 0        // K tile: 32 keys x 512 d            = 16384 shorts
#define LV 16384    // V tile: 512 dv x 32 keys           = 16384 shorts
#define LP 32768    // P: 64 q x stride 72                =  4608 shorts
#define LA 37376    // alpha[64] floats                   =   128 shorts
#define LL 37504    // l[64] floats                       =   128 shorts
#define LF 37632    // flags[4] ints                      =     8 shorts
#define LTOT 37648  // 75296 bytes

__global__ __launch_bounds__(256, 2) void attn2(
    const f16* __restrict__ Qh, const f16* __restrict__ Kh,
    const f16* __restrict__ Vt2, float* __restrict__ Y)
{
    __shared__ __align__(16) short sm[LTOT];

    const int tid  = threadIdx.x;
    const int lane = tid & 63;
    const int w    = tid >> 6;
    // XCD-aware decode: xcd = gid&7; b = (gid&7) + 8*(gid>>8); q0 = ((gid>>3)&31)*64
    const int gid  = blockIdx.x;
    const int b    = (gid & 7) + ((gid >> 8) << 3);
    const int q0   = ((gid >> 3) & 31) * 64;
    const int l15  = lane & 15;
    const int quad = lane >> 4;
    const int l31  = lane & 31;
    const int lhi  = lane >> 5;
    const int qhalf = w >> 1, dvhalf = w & 1;

    const f16* Khb  = Kh  + (size_t)b * SS * 512;
    const f16* Vt2b = Vt2 + (size_t)b * 64 * 512 * 32;

    // ---- Q fragments (resident): wave w, q rows q0+16w .. +15 ----
    half8 qh[16];
    {
        const half8* qhp = (const half8*)(Qh + ((size_t)(b * SS + q0 + w * 16 + l15)) * 512);
#pragma unroll
        for (int ks = 0; ks < 16; ++ks) qh[ks] = qhp[ks * 4 + quad];
    }

    f32x16 O[8];
#pragma unroll
    for (int n = 0; n < 8; ++n)
#pragma unroll
        for (int r = 0; r < 16; ++r) O[n][r] = 0.f;

    float m_pr[4] = {-1e30f, -1e30f, -1e30f, -1e30f};
    float l_r[4]  = {0.f, 0.f, 0.f, 0.f};

    auto stage_K = [&](int kb) {
#pragma unroll
        for (int i = 0; i < 8; ++i) {
            int key = w * 8 + i;
            const f16* g = Khb + ((size_t)(kb + key)) * 512 + ((lane ^ (key & 15)) << 3);
            GLOAD_LDS16(g, sm + LK + key * 512);
        }
    };
    // V: tile-major, identity staging (contiguous 1 KB per instruction)
    auto stage_V = [&](int t) {
        const f16* gbase = Vt2b + (size_t)t * 16384 + lane * 8;
#pragma unroll
        for (int i = 0; i < 8; ++i) {
            int off = (w * 8 + i) * 512;
            GLOAD_LDS16(gbase + off, sm + LV + off);
        }
    };

    float* aptr = (float*)(sm + LA);
    float* lptr = (float*)(sm + LL);
    int*   fptr = (int*)(sm + LF);

    stage_K(0);

    for (int t = 0; t < 64; ++t) {
        const int kb = t * 32;
        __syncthreads();              // K(t) staged; V buffer free
        stage_V(t);                   // overlaps score phase

        // ---- scores: S = Qh * Kh^T (16x16x32), 16 q x 32 keys per wave ----
        f32x4 S[2];
        S[0] = (f32x4){0.f, 0.f, 0.f, 0.f};
        S[1] = (f32x4){0.f, 0.f, 0.f, 0.f};
#pragma unroll
        for (int ks = 0; ks < 16; ++ks) {
#pragma unroll
            for (int n = 0; n < 2; ++n) {
                int key = n * 16 + l15;
                int ud  = ks * 4 + quad;
                half8 bf = *(const half8*)(sm + LK + key * 512 + ((ud ^ l15) << 3));
                S[n] = __builtin_amdgcn_mfma_f32_16x16x32_f16(qh[ks], bf, S[n], 0, 0, 0);
            }
        }

        // ---- online softmax ----
        float mx[4], sum[4], al[4];
#pragma unroll
        for (int r = 0; r < 4; ++r) mx[r] = fmaxf(S[0][r], S[1][r]);
#pragma unroll
        for (int off = 1; off < 16; off <<= 1)
#pragma unroll
            for (int r = 0; r < 4; ++r)
                mx[r] = fmaxf(mx[r], __shfl_xor(mx[r], off, 64));
#pragma unroll
        for (int r = 0; r < 4; ++r) {
            float mn = fmaxf(m_pr[r], mx[r]);
            al[r] = __expf(m_pr[r] - mn);
            m_pr[r] = mn;
            sum[r] = 0.f;
        }
#pragma unroll
        for (int n = 0; n < 2; ++n) {
#pragma unroll
            for (int r = 0; r < 4; ++r) {
                float p = __expf(S[n][r] - m_pr[r]);
                sum[r] += p;
                int q   = w * 16 + quad * 4 + r;
                int key = n * 16 + l15;
                *(f16*)(sm + LP + q * 72 + key) = (f16)p;
            }
        }
#pragma unroll
        for (int off = 1; off < 16; off <<= 1)
#pragma unroll
            for (int r = 0; r < 4; ++r)
                sum[r] += __shfl_xor(sum[r], off, 64);
#pragma unroll
        for (int r = 0; r < 4; ++r)
            l_r[r] = l_r[r] * al[r] + sum[r];
        bool any = (al[0] < 1.f) | (al[1] < 1.f) | (al[2] < 1.f) | (al[3] < 1.f);
        unsigned long long bm = __ballot(any);
        if (lane == 0) fptr[w] = (bm != 0ULL) ? 1 : 0;
        if (l15 == 0) {
#pragma unroll
            for (int r = 0; r < 4; ++r) aptr[w * 16 + quad * 4 + r] = al[r];
        }

        __syncthreads();              // V(t), P, alpha, flags ready; K free
        if (t < 63) stage_K(kb + 32); // overlaps PV phase

        // ---- O rescale (skipped when running max unchanged) ----
        if (fptr[2 * qhalf] | fptr[2 * qhalf + 1]) {
            float av[16];
#pragma unroll
            for (int r = 0; r < 16; ++r) {
                int row = (r & 3) + ((r >> 2) << 3) + (lhi << 2);
                av[r] = aptr[qhalf * 32 + row];
            }
#pragma unroll
            for (int n = 0; n < 8; ++n)
#pragma unroll
                for (int r = 0; r < 16; ++r) O[n][r] *= av[r];
        }

        // ---- PV: O += P * V (32x32x16), 32 q x 256 dv per wave ----
        half8 pA[2];
#pragma unroll
        for (int ks = 0; ks < 2; ++ks) {
            int q  = qhalf * 32 + l31;
            int uk = ks * 2 + lhi;
            pA[ks] = *(const half8*)(sm + LP + q * 72 + uk * 8);
        }
#pragma unroll
        for (int ks = 0; ks < 2; ++ks) {
#pragma unroll
            for (int n = 0; n < 8; ++n) {
                int dv = dvhalf * 256 + n * 32 + l31;
                int uk = ks * 2 + lhi;
                half8 bf = *(const half8*)(sm + LV + dv * 32 + ((uk ^ vperm(dv)) << 3));
                O[n] = __builtin_amdgcn_mfma_f32_32x32x16_f16(pA[ks], bf, O[n], 0, 0, 0);
            }
        }
    }

    // ---- epilogue: O /= l, store ----
    if (l15 == 0) {
#pragma unroll
        for (int r = 0; r < 4; ++r) lptr[w * 16 + quad * 4 + r] = l_r[r];
    }
    __syncthreads();
    float linv[16];
#pragma unroll
    for (int r = 0; r < 16; ++r) {
        int row = (r & 3) + ((r >> 2) << 3) + (lhi << 2);
        linv[r] = 1.0f / lptr[qhalf * 32 + row];
    }
#pragma unroll
    for (int n = 0; n < 8; ++n) {
#pragma unroll
        for (int r = 0; r < 16; ++r) {
            int row = (r & 3) + ((r >> 2) << 3) + (lhi << 2);
            Y[((size_t)(b * SS + q0 + qhalf * 32 + row)) * 512 + dvhalf * 256 + n * 32 + l31] =
                O[n][r] * linv[r];
        }
    }
}

// ---------------------------------------------------------------------------
// Host launcher
// ---------------------------------------------------------------------------
extern "C" void kernel_launch(void* const* d_in, const int* in_sizes, int n_in,
                              void* d_out, int out_size, void* d_ws, size_t ws_size,
                              hipStream_t stream)
{
    const float* x  = (const float*)d_in[0];
    const float* We = (const float*)d_in[1];
    const float* Wk = (const float*)d_in[2];
    const float* Wq = (const float*)d_in[3];
    const float* Wv = (const float*)d_in[4];
    float* out = (float*)d_out;

    const size_t WSZ = 3 * 256 * 512;          // 393216
    const size_t XSZ = (size_t)BB * SS * DIN;  // 8388608
    const size_t MSZ = (size_t)BB * SS * 512;  // 16777216

    f16* Wth = (f16*)d_ws;
    f16* Wtl = Wth + WSZ;
    f16* Xh  = Wtl + WSZ;
    f16* Xl  = Xh + XSZ;
    f16* Qh  = Xl + XSZ;
    f16* Kh  = Qh + MSZ;
    f16* Vt2 = Kh + MSZ;

    prep_x<<<dim3(XSZ / 4 / 256), dim3(256), 0, stream>>>(x, Xh, Xl);

    fuse_weights<<<dim3(1536), dim3(256), 0, stream>>>(We, Wk, Wq, Wv, Wth, Wtl);

    qkv_gemm<<<dim3(4, 256, 3), dim3(256), 0, stream>>>(
        Xh, Xl, Wth, Wtl, Kh, Qh, Vt2);

    attn2<<<dim3(512), dim3(256), 0, stream>>>(Qh, Kh, Vt2, out);
}